// Round 9
// baseline (652.192 us; speedup 1.0000x reference)
//
#include <hip/hip_runtime.h>
#include <math.h>

typedef unsigned int u32;
typedef unsigned short u16;
typedef __attribute__((ext_vector_type(8))) short short8v;   // 8 bf16 = 4 VGPR
typedef __attribute__((ext_vector_type(4))) float f32x4;

#define NDF 11
#define MAXN 35
#define RS 72          // padded LDS row stride in bf16 elems (144 B = 16B-aligned)

__device__ __forceinline__ u16 f2bf(float x) {
    u32 b = __float_as_uint(x);
    u32 r = (b + 0x7fffu + ((b >> 16) & 1u)) >> 16;
    return (u16)r;
}

// ---------------------------------------------------------------------------
// k_prep: single-bf16 transposed weight images + BN constants.
//   lint  [64][RS]     : lin^T   (n = h-index, k = input j; j>=33 -> 0)
//   w1t3  [3][64][RS]  : {nn1,nd1,pd1}^T  (n = o, k = h-index)
//   w2t3  [3][16][RS]  : head^T slices (n = out col, k = o)
// ---------------------------------------------------------------------------
__global__ void k_prep(const float* __restrict__ lin_w,
                       const float* __restrict__ nn1_w, const float* __restrict__ nn2_w,
                       const float* __restrict__ nd1_w, const float* __restrict__ nd2_w,
                       const float* __restrict__ pd1_w, const float* __restrict__ pd2_w,
                       const float* __restrict__ nd_g, const float* __restrict__ nd_be,
                       const float* __restrict__ nd_rm, const float* __restrict__ nd_rv,
                       const float* __restrict__ pd_g, const float* __restrict__ pd_be,
                       const float* __restrict__ pd_rm, const float* __restrict__ pd_rv,
                       u16* __restrict__ lint, u16* __restrict__ w1t3,
                       u16* __restrict__ w2t3, float* __restrict__ bnc,
                       int* __restrict__ cnt)
{
    const int t0 = blockIdx.x * 256 + threadIdx.x;     // 16 blocks -> 4096
    if (t0 == 0) cnt[0] = 0;
    if (t0 < 64) {
        const float sc = nd_g[t0] / sqrtf(nd_rv[t0] + 1e-5f);
        bnc[t0]       = sc;
        bnc[64 + t0]  = nd_be[t0] - nd_rm[t0] * sc;
        const float sp = pd_g[t0] / sqrtf(pd_rv[t0] + 1e-5f);
        bnc[128 + t0] = sp;
        bnc[192 + t0] = pd_be[t0] - pd_rm[t0] * sp;
    }
    for (int i = t0; i < 64*RS; i += 4096) {
        const int n = i / RS, k = i % RS;
        lint[i] = f2bf((k < 33) ? lin_w[k*64 + n] : 0.f);
    }
    for (int b = 0; b < 3; b++) {
        const float* M = (b == 0) ? nn1_w : (b == 1) ? nd1_w : pd1_w;
        u16* dst = w1t3 + (size_t)b * 64 * RS;
        for (int i = t0; i < 64*RS; i += 4096) {
            const int o = i / RS, k = i % RS;
            dst[i] = f2bf((k < 64) ? M[k*64 + o] : 0.f);
        }
        u16* d2 = w2t3 + (size_t)b * 16 * RS;
        for (int i = t0; i < 16*RS; i += 4096) {
            const int n = i / RS, k = i % RS;
            float v = 0.f;
            if (k < 64) {
                if (b == 0)      { if (n == 14)           v = nn2_w[k]; }
                else if (b == 1) { if (n < 11)            v = nd2_w[k*11 + n]; }
                else             { if (n >= 11 && n < 14) v = pd2_w[k*3 + (n-11)]; }
            }
            d2[i] = f2bf(v);
        }
    }
}

// ---------------------------------------------------------------------------
// k_mfma: 64 graphs/block, 4 waves (one 16-row M-band each). Single-bf16
// MFMA chain. All compute phases are band-private (each wave reads/writes
// only its own 16 rows of sA/sH) -> only 5 barriers, all gating weight
// staging. Weight buffers double-buffered for prefetch overlap.
// C/D layout (HW-verified m89): col=lane&15, row=(lane>>4)*4+reg.
// A/B frags use one consistent k-bijection -> sum is layout-independent.
// ---------------------------------------------------------------------------
__global__ __launch_bounds__(256)
void k_mfma(const float* __restrict__ z, const float* __restrict__ tpr,
            const float* __restrict__ lin_b,
            const u16* __restrict__ lint, const u16* __restrict__ w1t3,
            const u16* __restrict__ w2t3,
            const float* __restrict__ nn1_b, const float* __restrict__ nd1_b,
            const float* __restrict__ pd1_b,
            const float* __restrict__ nn2_b, const float* __restrict__ nd2_b,
            const float* __restrict__ pd2_b,
            const float* __restrict__ bnc,
            const float* __restrict__ nsc, const float* __restrict__ nsh,
            const float* __restrict__ psc, const float* __restrict__ psh,
            float* __restrict__ nf_g, float* __restrict__ pos_g,
            int* __restrict__ nn_int, float* __restrict__ out_nn,
            int* __restrict__ flagged, int* __restrict__ cnt, int B)
{
    __shared__ __align__(16) u16 sA[64*RS];      // X, later T (band-private)
    __shared__ __align__(16) u16 sH[64*RS];      // H          (band-private)
    __shared__ __align__(16) u16 sW[2][64*RS];   // weight double-buffer
    __shared__ __align__(16) u16 sW2[2][16*RS];  // head double-buffer
    __shared__ float s_linb[64], s_b1[3][64], s_sc[2][64], s_bi[2][64];

    const int t    = threadIdx.x;
    const int lane = t & 63;
    const int w    = t >> 6;
    const int g_lo = blockIdx.x * 64;

    // ---- stage X (bf16) + lint -> sW[0], branch0 -> sW[1]/sW2[0] ----
    {
        const float4* zb = (const float4*)(z + (size_t)g_lo * 32);
        const float4 v0 = zb[2*t], v1 = zb[2*t + 1];
        const float xv[8] = {v0.x, v0.y, v0.z, v0.w, v1.x, v1.y, v1.z, v1.w};
        const int g  = t >> 2;
        const int j0 = (t & 3) * 8;
        u32* hp = (u32*)(sA + g*RS + j0);
        #pragma unroll
        for (int q = 0; q < 4; q++)
            hp[q] = (u32)f2bf(xv[2*q]) | ((u32)f2bf(xv[2*q+1]) << 16);
        if (t < 64) {
            sA[t*RS + 32] = f2bf(tpr[g_lo + t]);
            sA[t*RS + 33] = 0;
            u32* zp = (u32*)(sA + t*RS + 34);
            #pragma unroll
            for (int q = 0; q < 19; q++) zp[q] = 0;
            s_linb[t]  = lin_b[t];
            s_b1[0][t] = nn1_b[t];
            s_b1[1][t] = nd1_b[t];
            s_b1[2][t] = pd1_b[t];
            s_sc[0][t] = bnc[t];       s_bi[0][t] = bnc[64 + t];
            s_sc[1][t] = bnc[128 + t]; s_bi[1][t] = bnc[192 + t];
        }
        const uint4* s0 = (const uint4*)lint;
        uint4* d0 = (uint4*)sW[0];
        for (int i = t; i < 64*RS/8; i += 256) d0[i] = s0[i];
        const uint4* s1 = (const uint4*)w1t3;
        uint4* d1 = (uint4*)sW[1];
        for (int i = t; i < 64*RS/8; i += 256) d1[i] = s1[i];
        const uint4* s2 = (const uint4*)w2t3;
        uint4* d2 = (uint4*)sW2[0];
        for (int i = t; i < 16*RS/8; i += 256) d2[i] = s2[i];
    }
    __syncthreads();

    auto ldfrag = [&](const u16* base, int row0, int ks) -> short8v {
        const uint4 v = *(const uint4*)(base + (row0 + (lane & 15))*RS + ks*32 + ((lane >> 4) * 8));
        return __builtin_bit_cast(short8v, v);
    };

    const int arow0 = w * 16;

    // ---- phase A: H = X @ lin + lin_b ----
    #pragma unroll 1
    for (int nt = 0; nt < 4; nt++) {
        f32x4 acc = {0.f, 0.f, 0.f, 0.f};
        #pragma unroll
        for (int ks = 0; ks < 2; ks++)
            acc = __builtin_amdgcn_mfma_f32_16x16x32_bf16(
                      ldfrag(sA, arow0, ks), ldfrag(sW[0], nt*16, ks), acc, 0, 0, 0);
        const int col = nt*16 + (lane & 15);
        const float bias = s_linb[col];
        #pragma unroll
        for (int r = 0; r < 4; r++)
            sH[(arow0 + (lane >> 4)*4 + r)*RS + col] = f2bf(acc[r] + bias);
    }
    __syncthreads();   // gates branch-1 weight prefetch overwriting sW[0]

    // ---- 3 branches: hidden -> T (sA), head accumulates acc2 ----
    f32x4 acc2 = {0.f, 0.f, 0.f, 0.f};
    #pragma unroll 1
    for (int b = 0; b < 3; b++) {
        if (b < 2) {   // prefetch next branch: weights -> sW[b&1], head -> sW2[(b+1)&1]
            const uint4* s1 = (const uint4*)(w1t3 + (size_t)(b+1) * 64 * RS);
            uint4* d1 = (uint4*)sW[b & 1];
            for (int i = t; i < 64*RS/8; i += 256) d1[i] = s1[i];
            const uint4* s2 = (const uint4*)(w2t3 + (size_t)(b+1) * 16 * RS);
            uint4* d2 = (uint4*)sW2[(b+1) & 1];
            for (int i = t; i < 16*RS/8; i += 256) d2[i] = s2[i];
        }
        const u16* wb = sW[(b+1) & 1];    // branch b weights: b0->sW[1], b1->sW[0], b2->sW[1]
        const u16* hb = sW2[b & 1];       // branch b head:    b0->sW2[0], b1->sW2[1], b2->sW2[0]

        #pragma unroll 1
        for (int nt = 0; nt < 4; nt++) {
            f32x4 acc = {0.f, 0.f, 0.f, 0.f};
            #pragma unroll
            for (int ks = 0; ks < 2; ks++)
                acc = __builtin_amdgcn_mfma_f32_16x16x32_bf16(
                          ldfrag(sH, arow0, ks), ldfrag(wb, nt*16, ks), acc, 0, 0, 0);
            const int col = nt*16 + (lane & 15);
            const float bb = s_b1[b][col];
            const float sc = (b > 0) ? s_sc[b-1][col] : 0.f;
            const float bi = (b > 0) ? s_bi[b-1][col] : 0.f;
            #pragma unroll
            for (int r = 0; r < 4; r++) {
                float rv = acc[r] + bb;
                rv = rv > 0.f ? rv : 0.f;
                const float tv = (b == 0) ? rv : fmaf(rv, sc, bi);
                sA[(arow0 + (lane >> 4)*4 + r)*RS + col] = f2bf(tv);
            }
        }
        // head (band-private RAW on sA; compiler inserts lgkmcnt)
        #pragma unroll
        for (int ks = 0; ks < 2; ks++)
            acc2 = __builtin_amdgcn_mfma_f32_16x16x32_bf16(
                       ldfrag(sA, arow0, ks), ldfrag(hb, 0, ks), acc2, 0, 0, 0);
        if (b < 2) __syncthreads();   // staged (b+1) buffers ready; sW reads done
    }

    // ---- epilogue: acc2 cols 0-10 = nf, 11-13 = pos, 14 = logit ----
    {
        const int col = lane & 15;
        const float nsc0 = nsc[0], nsh0 = nsh[0], psc0 = psc[0], psh0 = psh[0];
        #pragma unroll
        for (int r = 0; r < 4; r++) {
            const int row = arow0 + (lane >> 4)*4 + r;
            const int g = g_lo + row;
            const float v = acc2[r];
            if (col < 11) {
                nf_g[(size_t)g*NDF + col] = fmaf(v + nd2_b[col], nsc0, nsh0);
            } else if (col < 14) {
                pos_g[(size_t)g*3 + (col - 11)] = fmaf(v + pd2_b[col - 11], psc0, psh0);
            } else if (col == 14) {
                const float logit = v + nn2_b[0];
                const float arg = fmaf(1.f / (1.f + expf(-logit)), 30.f, 5.f);
                const int n = (int)arg;
                nn_int[g] = n;
                out_nn[g] = (float)n;
                if (fabsf(arg - rintf(arg)) < 0.30f) {   // wide margin; exact f64 fixup
                    const int i = atomicAdd(cnt, 1);
                    flagged[i] = g;
                }
            }
        }
    }
    (void)B;
}

// ---------------------------------------------------------------------------
// k_fix: exact f64 re-derivation of num_nodes for flagged graphs (one wave
// per graph; lane k computes h_k, shuffle-broadcast, butterfly reduce).
// ---------------------------------------------------------------------------
__global__ __launch_bounds__(256)
void k_fix(const float* __restrict__ z, const float* __restrict__ tpr,
           const float* __restrict__ lin_w, const float* __restrict__ lin_b,
           const float* __restrict__ nn1_w, const float* __restrict__ nn1_b,
           const float* __restrict__ nn2_w, const float* __restrict__ nn2_b,
           const int* __restrict__ flagged, const int* __restrict__ cnt,
           int* __restrict__ nn_int, float* __restrict__ out_nn)
{
    const int count = cnt[0];
    const int lane = threadIdx.x & 63;
    const int wv = (blockIdx.x * 256 + threadIdx.x) >> 6;   // 2048 waves
    const double b2 = (double)nn2_b[0];

    for (int w = wv; w < count; w += 2048) {
        const int g = flagged[w];

        double hk = (double)lin_b[lane];
        for (int j = 0; j < 32; j++)
            hk = fma((double)z[(size_t)g*32 + j], (double)lin_w[j*64 + lane], hk);
        hk = fma((double)tpr[g], (double)lin_w[32*64 + lane], hk);

        double a = (double)nn1_b[lane];
        for (int k = 0; k < 64; k++) {
            const double hks = __shfl(hk, k);
            a = fma(hks, (double)nn1_w[k*64 + lane], a);
        }
        double v = (a > 0.0) ? a * (double)nn2_w[lane] : 0.0;
        for (int d = 32; d > 0; d >>= 1) v += __shfl_xor(v, d);
        const double logit = v + b2;

        if (lane == 0) {
            const double sg = 1.0 / (1.0 + exp(-logit));
            const int n = (int)(sg * 30.0 + 5.0);
            nn_int[g] = n;
            out_nn[g] = (float)n;
        }
    }
}

// ---------------------------------------------------------------------------
// 2-kernel prefix sum: per-block inclusive (part) + block sums scan (boff,
// with boff[nb] = grand total).
// ---------------------------------------------------------------------------
__global__ __launch_bounds__(256)
void k_scan1(const int* __restrict__ a, int* __restrict__ part, int* __restrict__ bsum)
{
    __shared__ int s[256];
    const int t = threadIdx.x;
    const int g = blockIdx.x * 256 + t;
    const int v = a[g];
    s[t] = v;
    __syncthreads();
    for (int d = 1; d < 256; d <<= 1) {
        const int x = s[t];
        const int add = (t >= d) ? s[t - d] : 0;
        __syncthreads();
        s[t] = x + add;
        __syncthreads();
    }
    part[g] = s[t];
    if (t == 255) bsum[blockIdx.x] = s[255];
}

__global__ void k_scan2(const int* __restrict__ bsum, int* __restrict__ boff, int nb)
{
    __shared__ int s[1024];
    const int t = threadIdx.x;     // nb threads (512, pow2)
    const int v = bsum[t];
    s[t] = v;
    __syncthreads();
    for (int d = 1; d < nb; d <<= 1) {
        const int x = s[t];
        const int add = (t >= d) ? s[t - d] : 0;
        __syncthreads();
        s[t] = x + add;
        __syncthreads();
    }
    boff[t] = s[t] - v;            // exclusive
    if (t == nb - 1) boff[nb] = s[t];   // grand total sentinel
}

// ---------------------------------------------------------------------------
// k_expand: 2 rows/thread, two-level binary search (block offsets + local
// inclusive prefix), LDS repack, coalesced float4 stores.
// Rows >= total repeat graph B-1 (JAX total_repeat_length padding).
// ---------------------------------------------------------------------------
__global__ __launch_bounds__(256)
void k_expand(const int* __restrict__ part, const int* __restrict__ boff,
              const float* __restrict__ nf_g, const float* __restrict__ pos_g,
              float* __restrict__ out, int B, int T, int nb)
{
    __shared__ __align__(16) float s_nf[512*NDF];
    __shared__ __align__(16) float s_ps[512*3];
    const int t = threadIdx.x;
    const int r0 = blockIdx.x * 512 + 2*t;

    // level 1: block
    int blo = 0, bhi = nb - 1;
    while (blo < bhi) {
        const int m = (blo + bhi + 1) >> 1;
        if (boff[m] <= r0) blo = m; else bhi = m - 1;
    }
    const int bi = blo;
    const int lr = r0 - boff[bi];
    // level 2: within block (inclusive prefix part[])
    int lo = 0, hi2 = 256;
    while (lo < hi2) {
        const int m = (lo + hi2) >> 1;
        if (part[bi*256 + m] <= lr) lo = m + 1; else hi2 = m;
    }
    int i0 = bi*256 + lo;
    i0 = (i0 < B) ? i0 : B - 1;                       // padding rows -> last graph
    const int Ci0 = boff[i0 >> 8] + part[i0];         // global inclusive cumsum at i0
    const int i1 = ((r0 + 1) >= Ci0 && i0 < B - 1) ? i0 + 1 : i0;

    #pragma unroll
    for (int j = 0; j < NDF; j++) {
        s_nf[(2*t)*NDF + j]     = nf_g[(size_t)i0*NDF + j];
        s_nf[(2*t + 1)*NDF + j] = nf_g[(size_t)i1*NDF + j];
    }
    #pragma unroll
    for (int j = 0; j < 3; j++) {
        s_ps[(2*t)*3 + j]     = pos_g[(size_t)i0*3 + j];
        s_ps[(2*t + 1)*3 + j] = pos_g[(size_t)i1*3 + j];
    }
    __syncthreads();

    float4* onf = (float4*)(out + (size_t)blockIdx.x * 512 * NDF);
    const float4* snf = (const float4*)s_nf;
    #pragma unroll
    for (int q = 0; q < 6; q++) {
        const int idx = q*256 + t;
        if (idx < 512*NDF/4) onf[idx] = snf[idx];
    }
    float4* ops = (float4*)(out + (size_t)T*NDF + (size_t)blockIdx.x * 512 * 3);
    const float4* sps = (const float4*)s_ps;
    #pragma unroll
    for (int q = 0; q < 2; q++) {
        const int idx = q*256 + t;
        if (idx < 384) ops[idx] = sps[idx];
    }
}

// ---------------------------------------------------------------------------
extern "C" void kernel_launch(void* const* d_in, const int* in_sizes, int n_in,
                              void* d_out, int out_size, void* d_ws, size_t ws_size,
                              hipStream_t stream)
{
    const float* z     = (const float*)d_in[0];
    const float* tpr   = (const float*)d_in[1];
    const int    B     = in_sizes[1];
    const int    T     = B * MAXN;

    const float* lin_w = (const float*)d_in[3];
    const float* lin_b = (const float*)d_in[4];
    const float* nn1_w = (const float*)d_in[5];
    const float* nn1_b = (const float*)d_in[6];
    const float* nn2_w = (const float*)d_in[7];
    const float* nn2_b = (const float*)d_in[8];
    const float* nd1_w = (const float*)d_in[9];
    const float* nd1_b = (const float*)d_in[10];
    const float* nd_g  = (const float*)d_in[11];
    const float* nd_be = (const float*)d_in[12];
    const float* nd_rm = (const float*)d_in[13];
    const float* nd_rv = (const float*)d_in[14];
    const float* nd2_w = (const float*)d_in[15];
    const float* nd2_b = (const float*)d_in[16];
    const float* pd1_w = (const float*)d_in[17];
    const float* pd1_b = (const float*)d_in[18];
    const float* pd_g  = (const float*)d_in[19];
    const float* pd_be = (const float*)d_in[20];
    const float* pd_rm = (const float*)d_in[21];
    const float* pd_rv = (const float*)d_in[22];
    const float* pd2_w = (const float*)d_in[23];
    const float* pd2_b = (const float*)d_in[24];
    const float* nsc   = (const float*)d_in[25];
    const float* nsh   = (const float*)d_in[26];
    const float* psc   = (const float*)d_in[27];
    const float* psh   = (const float*)d_in[28];

    float* out = (float*)d_out;

    char* wsp = (char*)d_ws;
    size_t off = 0;
    auto take = [&](size_t bytes) { void* p = wsp + off; off = (off + bytes + 255) & ~(size_t)255; return p; };

    u16*   lint  = (u16*)take(64*RS*sizeof(u16));            //  9216 B
    u16*   w1t3  = (u16*)take(3*64*RS*sizeof(u16));          // 27648 B
    u16*   w2t3  = (u16*)take(3*16*RS*sizeof(u16));          //  6912 B
    float* bnc   = (float*)take(256*sizeof(float));
    int*   cnt   = (int*)take(256);
    float* nf_g  = (float*)take((size_t)B*NDF*sizeof(float));
    float* pos_g = (float*)take((size_t)B*3*sizeof(float));
    int*   nn_i  = (int*)take((size_t)B*sizeof(int));
    int*   part  = (int*)take((size_t)B*sizeof(int));
    int*   bsum  = (int*)take(4096*sizeof(int));
    int*   boff  = (int*)take(4096*sizeof(int));
    int*   flagged = part;   // k_fix consumes flagged BEFORE scan1 writes part

    const int nb = B / 256;   // 512

    k_prep<<<16, 256, 0, stream>>>(lin_w, nn1_w, nn2_w, nd1_w, nd2_w, pd1_w, pd2_w,
                                   nd_g, nd_be, nd_rm, nd_rv,
                                   pd_g, pd_be, pd_rm, pd_rv,
                                   lint, w1t3, w2t3, bnc, cnt);

    k_mfma<<<B/64, 256, 0, stream>>>(z, tpr, lin_b, lint, w1t3, w2t3,
                                     nn1_b, nd1_b, pd1_b, nn2_b, nd2_b, pd2_b,
                                     bnc, nsc, nsh, psc, psh,
                                     nf_g, pos_g, nn_i, out + (size_t)T*14,
                                     flagged, cnt, B);

    k_fix<<<512, 256, 0, stream>>>(z, tpr, lin_w, lin_b, nn1_w, nn1_b, nn2_w, nn2_b,
                                   flagged, cnt, nn_i, out + (size_t)T*14);

    k_scan1<<<nb, 256, 0, stream>>>(nn_i, part, bsum);
    k_scan2<<<1, nb, 0, stream>>>(bsum, boff, nb);

    k_expand<<<T/512, 256, 0, stream>>>(part, boff, nf_g, pos_g, out, B, T, nb);

    (void)n_in; (void)out_size; (void)ws_size;
}

// Round 10
// 586.045 us; speedup vs baseline: 1.1129x; 1.1129x over previous
//
#include <hip/hip_runtime.h>
#include <math.h>

typedef unsigned int u32;
typedef unsigned short u16;
typedef __attribute__((ext_vector_type(8))) short short8v;   // 8 bf16 = 4 VGPR
typedef __attribute__((ext_vector_type(4))) float f32x4;

#define NDF 11
#define MAXN 35
#define RS 72          // padded row stride in bf16 elems (144 B; 144 = 16*9 -> 16B-aligned rows)

__device__ __forceinline__ u16 f2bf(float x) {
    u32 b = __float_as_uint(x);
    u32 r = (b + 0x7fffu + ((b >> 16) & 1u)) >> 16;
    return (u16)r;
}

// ---------------------------------------------------------------------------
// k_prep: single-bf16 transposed weight images + BN constants.
//   lint  [64][RS]    : lin^T   (n = h-index, k = input j; j>=33 -> 0)
//   w1t3  [3][64][RS] : {nn1,nd1,pd1}^T  (n = o, k = h-index)
//   w2t3  [3][16][RS] : head^T slices (n = out col, k = o); unused cols -> 0
// ---------------------------------------------------------------------------
__global__ void k_prep(const float* __restrict__ lin_w,
                       const float* __restrict__ nn1_w, const float* __restrict__ nn2_w,
                       const float* __restrict__ nd1_w, const float* __restrict__ nd2_w,
                       const float* __restrict__ pd1_w, const float* __restrict__ pd2_w,
                       const float* __restrict__ nd_g, const float* __restrict__ nd_be,
                       const float* __restrict__ nd_rm, const float* __restrict__ nd_rv,
                       const float* __restrict__ pd_g, const float* __restrict__ pd_be,
                       const float* __restrict__ pd_rm, const float* __restrict__ pd_rv,
                       u16* __restrict__ lint, u16* __restrict__ w1t3,
                       u16* __restrict__ w2t3, float* __restrict__ bnc,
                       int* __restrict__ cnt)
{
    const int t0 = blockIdx.x * 256 + threadIdx.x;     // 16 blocks -> 4096
    if (t0 == 0) cnt[0] = 0;
    if (t0 < 64) {
        const float sc = nd_g[t0] / sqrtf(nd_rv[t0] + 1e-5f);
        bnc[t0]       = sc;
        bnc[64 + t0]  = nd_be[t0] - nd_rm[t0] * sc;
        const float sp = pd_g[t0] / sqrtf(pd_rv[t0] + 1e-5f);
        bnc[128 + t0] = sp;
        bnc[192 + t0] = pd_be[t0] - pd_rm[t0] * sp;
    }
    for (int i = t0; i < 64*RS; i += 4096) {
        const int n = i / RS, k = i % RS;
        lint[i] = f2bf((k < 33) ? lin_w[k*64 + n] : 0.f);
    }
    for (int b = 0; b < 3; b++) {
        const float* M = (b == 0) ? nn1_w : (b == 1) ? nd1_w : pd1_w;
        u16* dst = w1t3 + (size_t)b * 64 * RS;
        for (int i = t0; i < 64*RS; i += 4096) {
            const int o = i / RS, k = i % RS;
            dst[i] = f2bf((k < 64) ? M[k*64 + o] : 0.f);
        }
        u16* d2 = w2t3 + (size_t)b * 16 * RS;
        for (int i = t0; i < 16*RS; i += 4096) {
            const int n = i / RS, k = i % RS;
            float v = 0.f;
            if (k < 64) {
                if (b == 0)      { if (n == 14)           v = nn2_w[k]; }
                else if (b == 1) { if (n < 11)            v = nd2_w[k*11 + n]; }
                else             { if (n >= 11 && n < 14) v = pd2_w[k*3 + (n-11)]; }
            }
            d2[i] = f2bf(v);
        }
    }
}

// ---------------------------------------------------------------------------
// k_mfma: fully wave-independent. Each wave: 2 chunks x 16 graphs, private
// LDS slices (sX/sH/sT), ALL weight fragments pre-loaded into VGPRs from the
// global bf16 images (same k-bijection as the A-side ldfrag -> pairing holds).
// NO __syncthreads anywhere. C/D layout (m89): col=lane&15, row=(lane>>4)*4+reg.
// ---------------------------------------------------------------------------
__global__ __launch_bounds__(256)
void k_mfma(const float* __restrict__ z, const float* __restrict__ tpr,
            const float* __restrict__ lin_b,
            const u16* __restrict__ lint, const u16* __restrict__ w1t3,
            const u16* __restrict__ w2t3,
            const float* __restrict__ nn1_b, const float* __restrict__ nd1_b,
            const float* __restrict__ pd1_b,
            const float* __restrict__ nn2_b, const float* __restrict__ nd2_b,
            const float* __restrict__ pd2_b,
            const float* __restrict__ bnc,
            const float* __restrict__ nsc, const float* __restrict__ nsh,
            const float* __restrict__ psc, const float* __restrict__ psh,
            float* __restrict__ nf_g, float* __restrict__ pos_g,
            int* __restrict__ nn_int, float* __restrict__ out_nn,
            int* __restrict__ flagged, int* __restrict__ cnt, int B)
{
    __shared__ __align__(16) u16 sX[4][16*RS];   // per-wave X slice
    __shared__ __align__(16) u16 sH[4][16*RS];   // per-wave H slice
    __shared__ __align__(16) u16 sT[4][16*RS];   // per-wave T slice

    const int t    = threadIdx.x;
    const int lane = t & 63;
    const int w    = t >> 6;
    u16* mX = sX[w];
    u16* mH = sH[w];
    u16* mT = sT[w];

    const int W = blockIdx.x * 4 + w;            // global wave id, 0..4095

    // ---- zero X pad cols 33..63 once (chunks rewrite only cols 0..32) ----
    if (lane < 16) {
        mX[lane*RS + 33] = 0;
        u32* p = (u32*)(mX + lane*RS + 34);      // cols 34..63 = 15 u32
        #pragma unroll
        for (int q = 0; q < 15; q++) p[q] = 0;
    }

    // ---- preload ALL weight fragments into registers (global, L2-hot) ----
    auto gfrag = [&](const u16* base, int row0, int ks) -> short8v {
        const uint4 v = *(const uint4*)(base + (row0 + (lane & 15))*RS + ks*32 + ((lane >> 4) * 8));
        return __builtin_bit_cast(short8v, v);
    };
    short8v fLin[4][2], fW[3][4][2], fH2[3][2];
    #pragma unroll
    for (int nt = 0; nt < 4; nt++)
        #pragma unroll
        for (int ks = 0; ks < 2; ks++)
            fLin[nt][ks] = gfrag(lint, nt*16, ks);
    #pragma unroll
    for (int b = 0; b < 3; b++)
        #pragma unroll
        for (int nt = 0; nt < 4; nt++)
            #pragma unroll
            for (int ks = 0; ks < 2; ks++)
                fW[b][nt][ks] = gfrag(w1t3 + (size_t)b*64*RS, nt*16, ks);
    #pragma unroll
    for (int b = 0; b < 3; b++)
        #pragma unroll
        for (int ks = 0; ks < 2; ks++)
            fH2[b][ks] = gfrag(w2t3 + (size_t)b*16*RS, 0, ks);

    // ---- per-lane constants (col-dependent biases) ----
    const int col = lane & 15;
    float bLin[4], bB1[3][4], bSc[2][4], bBi[2][4];
    #pragma unroll
    for (int nt = 0; nt < 4; nt++) {
        const int c = nt*16 + col;
        bLin[nt]    = lin_b[c];
        bB1[0][nt]  = nn1_b[c];
        bB1[1][nt]  = nd1_b[c];
        bB1[2][nt]  = pd1_b[c];
        bSc[0][nt]  = bnc[c];        bBi[0][nt] = bnc[64 + c];
        bSc[1][nt]  = bnc[128 + c];  bBi[1][nt] = bnc[192 + c];
    }
    const float epb = (col < 11) ? nd2_b[col] : (col < 14) ? pd2_b[col - 11] : 0.f;
    const float nn2b = nn2_b[0];
    const float a_ns = nsc[0], a_nh = nsh[0], a_ps = psc[0], a_ph = psh[0];

    auto ldfrag = [&](const u16* base, int ks) -> short8v {
        const uint4 v = *(const uint4*)(base + (lane & 15)*RS + ks*32 + ((lane >> 4) * 8));
        return __builtin_bit_cast(short8v, v);
    };

    // ---- 2 chunks of 16 graphs, fully wave-private ----
    #pragma unroll 1
    for (int c = 0; c < 2; c++) {
        const int gb = (W*2 + c) * 16;
        if (gb >= B) break;

        // stage X: lane reads 8 floats of graph gb+(lane>>2), packs one b128 row-slice
        {
            const float4* zb = (const float4*)(z + (size_t)gb * 32);
            const float4 v0 = zb[(lane >> 2)*8 + (lane & 3)*2];
            const float4 v1 = zb[(lane >> 2)*8 + (lane & 3)*2 + 1];
            const float xv[8] = {v0.x, v0.y, v0.z, v0.w, v1.x, v1.y, v1.z, v1.w};
            u32 pk[4];
            #pragma unroll
            for (int q = 0; q < 4; q++)
                pk[q] = (u32)f2bf(xv[2*q]) | ((u32)f2bf(xv[2*q+1]) << 16);
            *(uint4*)(mX + (lane >> 2)*RS + (lane & 3)*8) = *(uint4*)pk;
            if (lane < 16) mX[lane*RS + 32] = f2bf(tpr[gb + lane]);
        }

        // phase A: H = X @ lin + lin_b
        const short8v a0 = ldfrag(mX, 0);
        const short8v a1 = ldfrag(mX, 1);
        #pragma unroll
        for (int nt = 0; nt < 4; nt++) {
            f32x4 acc = {0.f, 0.f, 0.f, 0.f};
            acc = __builtin_amdgcn_mfma_f32_16x16x32_bf16(a0, fLin[nt][0], acc, 0, 0, 0);
            acc = __builtin_amdgcn_mfma_f32_16x16x32_bf16(a1, fLin[nt][1], acc, 0, 0, 0);
            const float bias = bLin[nt];
            #pragma unroll
            for (int r = 0; r < 4; r++)
                mH[((lane >> 4)*4 + r)*RS + nt*16 + col] = f2bf(acc[r] + bias);
        }

        // branches
        const short8v h0 = ldfrag(mH, 0);
        const short8v h1 = ldfrag(mH, 1);
        f32x4 acc2 = {0.f, 0.f, 0.f, 0.f};
        #pragma unroll
        for (int b = 0; b < 3; b++) {
            #pragma unroll
            for (int nt = 0; nt < 4; nt++) {
                f32x4 acc = {0.f, 0.f, 0.f, 0.f};
                acc = __builtin_amdgcn_mfma_f32_16x16x32_bf16(h0, fW[b][nt][0], acc, 0, 0, 0);
                acc = __builtin_amdgcn_mfma_f32_16x16x32_bf16(h1, fW[b][nt][1], acc, 0, 0, 0);
                const float bb = bB1[b][nt];
                const float sc = (b > 0) ? bSc[b-1][nt] : 0.f;
                const float bi = (b > 0) ? bBi[b-1][nt] : 0.f;
                #pragma unroll
                for (int r = 0; r < 4; r++) {
                    float rv = acc[r] + bb;
                    rv = rv > 0.f ? rv : 0.f;
                    const float tv = (b == 0) ? rv : fmaf(rv, sc, bi);
                    mT[((lane >> 4)*4 + r)*RS + nt*16 + col] = f2bf(tv);
                }
            }
            const short8v t0 = ldfrag(mT, 0);
            const short8v t1 = ldfrag(mT, 1);
            acc2 = __builtin_amdgcn_mfma_f32_16x16x32_bf16(t0, fH2[b][0], acc2, 0, 0, 0);
            acc2 = __builtin_amdgcn_mfma_f32_16x16x32_bf16(t1, fH2[b][1], acc2, 0, 0, 0);
        }

        // epilogue: cols 0-10 nf, 11-13 pos, 14 logit
        #pragma unroll
        for (int r = 0; r < 4; r++) {
            const int g = gb + (lane >> 4)*4 + r;
            const float v = acc2[r];
            if (col < 11) {
                nf_g[(size_t)g*NDF + col] = fmaf(v + epb, a_ns, a_nh);
            } else if (col < 14) {
                pos_g[(size_t)g*3 + (col - 11)] = fmaf(v + epb, a_ps, a_ph);
            } else if (col == 14) {
                const float logit = v + nn2b;
                const float arg = fmaf(1.f / (1.f + expf(-logit)), 30.f, 5.f);
                const int n = (int)arg;
                nn_int[g] = n;
                out_nn[g] = (float)n;
                if (fabsf(arg - rintf(arg)) < 0.30f) {   // wide margin; exact f64 fixup below
                    const int i = atomicAdd(cnt, 1);
                    flagged[i] = g;
                }
            }
        }
    }
    (void)B;
}

// ---------------------------------------------------------------------------
// k_fix: exact f64 re-derivation of num_nodes for flagged graphs. One wave
// per graph; 4 independent fma chains per dot to break latency serialization.
// ---------------------------------------------------------------------------
__global__ __launch_bounds__(256)
void k_fix(const float* __restrict__ z, const float* __restrict__ tpr,
           const float* __restrict__ lin_w, const float* __restrict__ lin_b,
           const float* __restrict__ nn1_w, const float* __restrict__ nn1_b,
           const float* __restrict__ nn2_w, const float* __restrict__ nn2_b,
           const int* __restrict__ flagged, const int* __restrict__ cnt,
           int* __restrict__ nn_int, float* __restrict__ out_nn)
{
    const int count = cnt[0];
    const int lane = threadIdx.x & 63;
    const int wv = (blockIdx.x * 256 + threadIdx.x) >> 6;   // 4096 waves
    const double b2 = (double)nn2_b[0];

    for (int w = wv; w < count; w += 4096) {
        const int g = flagged[w];

        // lane k computes h_k in f64 (4 chains over j)
        double h0 = (double)lin_b[lane], h1 = 0.0, h2 = 0.0, h3 = 0.0;
        for (int j = 0; j < 32; j += 4) {
            h0 = fma((double)z[(size_t)g*32 + j],     (double)lin_w[j*64 + lane],     h0);
            h1 = fma((double)z[(size_t)g*32 + j + 1], (double)lin_w[(j+1)*64 + lane], h1);
            h2 = fma((double)z[(size_t)g*32 + j + 2], (double)lin_w[(j+2)*64 + lane], h2);
            h3 = fma((double)z[(size_t)g*32 + j + 3], (double)lin_w[(j+3)*64 + lane], h3);
        }
        h0 = fma((double)tpr[g], (double)lin_w[32*64 + lane], h0);
        const double hk = (h0 + h1) + (h2 + h3);

        // lane o: a_o = nn1_b[o] + sum_k h_k * w1[k][o]  (4 chains)
        double a0 = (double)nn1_b[lane], a1 = 0.0, a2 = 0.0, a3 = 0.0;
        for (int k = 0; k < 64; k += 4) {
            a0 = fma(__shfl(hk, k),     (double)nn1_w[k*64 + lane],     a0);
            a1 = fma(__shfl(hk, k + 1), (double)nn1_w[(k+1)*64 + lane], a1);
            a2 = fma(__shfl(hk, k + 2), (double)nn1_w[(k+2)*64 + lane], a2);
            a3 = fma(__shfl(hk, k + 3), (double)nn1_w[(k+3)*64 + lane], a3);
        }
        const double a = (a0 + a1) + (a2 + a3);
        double v = (a > 0.0) ? a * (double)nn2_w[lane] : 0.0;
        for (int d = 32; d > 0; d >>= 1) v += __shfl_xor(v, d);
        const double logit = v + b2;

        if (lane == 0) {
            const double sg = 1.0 / (1.0 + exp(-logit));
            const int n = (int)(sg * 30.0 + 5.0);
            nn_int[g] = n;
            out_nn[g] = (float)n;
        }
    }
}

// ---------------------------------------------------------------------------
// 2-kernel prefix sum: per-block inclusive (part) + block-sum scan (boff).
// ---------------------------------------------------------------------------
__global__ __launch_bounds__(256)
void k_scan1(const int* __restrict__ a, int* __restrict__ part, int* __restrict__ bsum)
{
    __shared__ int s[256];
    const int t = threadIdx.x;
    const int g = blockIdx.x * 256 + t;
    const int v = a[g];
    s[t] = v;
    __syncthreads();
    for (int d = 1; d < 256; d <<= 1) {
        const int x = s[t];
        const int add = (t >= d) ? s[t - d] : 0;
        __syncthreads();
        s[t] = x + add;
        __syncthreads();
    }
    part[g] = s[t];
    if (t == 255) bsum[blockIdx.x] = s[255];
}

__global__ void k_scan2(const int* __restrict__ bsum, int* __restrict__ boff, int nb)
{
    __shared__ int s[1024];
    const int t = threadIdx.x;     // nb threads (512)
    const int v = bsum[t];
    s[t] = v;
    __syncthreads();
    for (int d = 1; d < nb; d <<= 1) {
        const int x = s[t];
        const int add = (t >= d) ? s[t - d] : 0;
        __syncthreads();
        s[t] = x + add;
        __syncthreads();
    }
    boff[t] = s[t] - v;            // exclusive
    if (t == nb - 1) boff[nb] = s[t];
}

// ---------------------------------------------------------------------------
// k_expand: 2 rows/thread, two-level binary search, LDS repack, float4 stores.
// Rows >= total repeat graph B-1 (JAX total_repeat_length padding).
// ---------------------------------------------------------------------------
__global__ __launch_bounds__(256)
void k_expand(const int* __restrict__ part, const int* __restrict__ boff,
              const float* __restrict__ nf_g, const float* __restrict__ pos_g,
              float* __restrict__ out, int B, int T, int nb)
{
    __shared__ __align__(16) float s_nf[512*NDF];
    __shared__ __align__(16) float s_ps[512*3];
    const int t = threadIdx.x;
    const int r0 = blockIdx.x * 512 + 2*t;

    int blo = 0, bhi = nb - 1;
    while (blo < bhi) {
        const int m = (blo + bhi + 1) >> 1;
        if (boff[m] <= r0) blo = m; else bhi = m - 1;
    }
    const int bi = blo;
    const int lr = r0 - boff[bi];
    int lo = 0, hi2 = 256;
    while (lo < hi2) {
        const int m = (lo + hi2) >> 1;
        if (part[bi*256 + m] <= lr) lo = m + 1; else hi2 = m;
    }
    int i0 = bi*256 + lo;
    i0 = (i0 < B) ? i0 : B - 1;
    const int Ci0 = boff[i0 >> 8] + part[i0];
    const int i1 = ((r0 + 1) >= Ci0 && i0 < B - 1) ? i0 + 1 : i0;

    #pragma unroll
    for (int j = 0; j < NDF; j++) {
        s_nf[(2*t)*NDF + j]     = nf_g[(size_t)i0*NDF + j];
        s_nf[(2*t + 1)*NDF + j] = nf_g[(size_t)i1*NDF + j];
    }
    #pragma unroll
    for (int j = 0; j < 3; j++) {
        s_ps[(2*t)*3 + j]     = pos_g[(size_t)i0*3 + j];
        s_ps[(2*t + 1)*3 + j] = pos_g[(size_t)i1*3 + j];
    }
    __syncthreads();

    float4* onf = (float4*)(out + (size_t)blockIdx.x * 512 * NDF);
    const float4* snf = (const float4*)s_nf;
    #pragma unroll
    for (int q = 0; q < 6; q++) {
        const int idx = q*256 + t;
        if (idx < 512*NDF/4) onf[idx] = snf[idx];
    }
    float4* ops = (float4*)(out + (size_t)T*NDF + (size_t)blockIdx.x * 512 * 3);
    const float4* sps = (const float4*)s_ps;
    #pragma unroll
    for (int q = 0; q < 2; q++) {
        const int idx = q*256 + t;
        if (idx < 384) ops[idx] = sps[idx];
    }
}

// ---------------------------------------------------------------------------
extern "C" void kernel_launch(void* const* d_in, const int* in_sizes, int n_in,
                              void* d_out, int out_size, void* d_ws, size_t ws_size,
                              hipStream_t stream)
{
    const float* z     = (const float*)d_in[0];
    const float* tpr   = (const float*)d_in[1];
    const int    B     = in_sizes[1];
    const int    T     = B * MAXN;

    const float* lin_w = (const float*)d_in[3];
    const float* lin_b = (const float*)d_in[4];
    const float* nn1_w = (const float*)d_in[5];
    const float* nn1_b = (const float*)d_in[6];
    const float* nn2_w = (const float*)d_in[7];
    const float* nn2_b = (const float*)d_in[8];
    const float* nd1_w = (const float*)d_in[9];
    const float* nd1_b = (const float*)d_in[10];
    const float* nd_g  = (const float*)d_in[11];
    const float* nd_be = (const float*)d_in[12];
    const float* nd_rm = (const float*)d_in[13];
    const float* nd_rv = (const float*)d_in[14];
    const float* nd2_w = (const float*)d_in[15];
    const float* nd2_b = (const float*)d_in[16];
    const float* pd1_w = (const float*)d_in[17];
    const float* pd1_b = (const float*)d_in[18];
    const float* pd_g  = (const float*)d_in[19];
    const float* pd_be = (const float*)d_in[20];
    const float* pd_rm = (const float*)d_in[21];
    const float* pd_rv = (const float*)d_in[22];
    const float* pd2_w = (const float*)d_in[23];
    const float* pd2_b = (const float*)d_in[24];
    const float* nsc   = (const float*)d_in[25];
    const float* nsh   = (const float*)d_in[26];
    const float* psc   = (const float*)d_in[27];
    const float* psh   = (const float*)d_in[28];

    float* out = (float*)d_out;

    char* wsp = (char*)d_ws;
    size_t off = 0;
    auto take = [&](size_t bytes) { void* p = wsp + off; off = (off + bytes + 255) & ~(size_t)255; return p; };

    u16*   lint  = (u16*)take(64*RS*sizeof(u16));
    u16*   w1t3  = (u16*)take(3*64*RS*sizeof(u16));
    u16*   w2t3  = (u16*)take(3*16*RS*sizeof(u16));
    float* bnc   = (float*)take(256*sizeof(float));
    int*   cnt   = (int*)take(256);
    float* nf_g  = (float*)take((size_t)B*NDF*sizeof(float));
    float* pos_g = (float*)take((size_t)B*3*sizeof(float));
    int*   nn_i  = (int*)take((size_t)B*sizeof(int));
    int*   part  = (int*)take((size_t)B*sizeof(int));
    int*   bsum  = (int*)take(4096*sizeof(int));
    int*   boff  = (int*)take(4096*sizeof(int));
    int*   flagged = part;   // k_fix consumes flagged BEFORE scan1 writes part

    const int nb = B / 256;   // 512

    k_prep<<<16, 256, 0, stream>>>(lin_w, nn1_w, nn2_w, nd1_w, nd2_w, pd1_w, pd2_w,
                                   nd_g, nd_be, nd_rm, nd_rv,
                                   pd_g, pd_be, pd_rm, pd_rv,
                                   lint, w1t3, w2t3, bnc, cnt);

    k_mfma<<<B/128, 256, 0, stream>>>(z, tpr, lin_b, lint, w1t3, w2t3,
                                      nn1_b, nd1_b, pd1_b, nn2_b, nd2_b, pd2_b,
                                      bnc, nsc, nsh, psc, psh,
                                      nf_g, pos_g, nn_i, out + (size_t)T*14,
                                      flagged, cnt, B);

    k_fix<<<1024, 256, 0, stream>>>(z, tpr, lin_w, lin_b, nn1_w, nn1_b, nn2_w, nn2_b,
                                    flagged, cnt, nn_i, out + (size_t)T*14);

    k_scan1<<<nb, 256, 0, stream>>>(nn_i, part, bsum);
    k_scan2<<<1, nb, 0, stream>>>(bsum, boff, nb);

    k_expand<<<T/512, 256, 0, stream>>>(part, boff, nf_g, pos_g, out, B, T, nb);

    (void)n_in; (void)out_size; (void)ws_size;
}

// Round 11
// 207.446 us; speedup vs baseline: 3.1439x; 2.8250x over previous
//
#include <hip/hip_runtime.h>
#include <math.h>

typedef unsigned int u32;
typedef unsigned short u16;
typedef unsigned char u8;
typedef __attribute__((ext_vector_type(8))) short short8v;   // 8 bf16 = 4 VGPR
typedef __attribute__((ext_vector_type(4))) float f32x4;

#define NDF 11
#define MAXN 35
#define RS 72          // padded row stride in bf16 elems (144 B; 16B-aligned rows)

__device__ __forceinline__ u16 f2bf(float x) {
    u32 b = __float_as_uint(x);
    u32 r = (b + 0x7fffu + ((b >> 16) & 1u)) >> 16;
    return (u16)r;
}

// ---------------------------------------------------------------------------
// k_prep: single-bf16 transposed weight images + BN constants.
// ---------------------------------------------------------------------------
__global__ void k_prep(const float* __restrict__ lin_w,
                       const float* __restrict__ nn1_w, const float* __restrict__ nn2_w,
                       const float* __restrict__ nd1_w, const float* __restrict__ nd2_w,
                       const float* __restrict__ pd1_w, const float* __restrict__ pd2_w,
                       const float* __restrict__ nd_g, const float* __restrict__ nd_be,
                       const float* __restrict__ nd_rm, const float* __restrict__ nd_rv,
                       const float* __restrict__ pd_g, const float* __restrict__ pd_be,
                       const float* __restrict__ pd_rm, const float* __restrict__ pd_rv,
                       u16* __restrict__ lint, u16* __restrict__ w1t3,
                       u16* __restrict__ w2t3, float* __restrict__ bnc)
{
    const int t0 = blockIdx.x * 256 + threadIdx.x;     // 16 blocks -> 4096
    if (t0 < 64) {
        const float sc = nd_g[t0] / sqrtf(nd_rv[t0] + 1e-5f);
        bnc[t0]       = sc;
        bnc[64 + t0]  = nd_be[t0] - nd_rm[t0] * sc;
        const float sp = pd_g[t0] / sqrtf(pd_rv[t0] + 1e-5f);
        bnc[128 + t0] = sp;
        bnc[192 + t0] = pd_be[t0] - pd_rm[t0] * sp;
    }
    for (int i = t0; i < 64*RS; i += 4096) {
        const int n = i / RS, k = i % RS;
        lint[i] = f2bf((k < 33) ? lin_w[k*64 + n] : 0.f);
    }
    for (int b = 0; b < 3; b++) {
        const float* M = (b == 0) ? nn1_w : (b == 1) ? nd1_w : pd1_w;
        u16* dst = w1t3 + (size_t)b * 64 * RS;
        for (int i = t0; i < 64*RS; i += 4096) {
            const int o = i / RS, k = i % RS;
            dst[i] = f2bf((k < 64) ? M[k*64 + o] : 0.f);
        }
        u16* d2 = w2t3 + (size_t)b * 16 * RS;
        for (int i = t0; i < 16*RS; i += 4096) {
            const int n = i / RS, k = i % RS;
            float v = 0.f;
            if (k < 64) {
                if (b == 0)      { if (n == 14)           v = nn2_w[k]; }
                else if (b == 1) { if (n < 11)            v = nd2_w[k*11 + n]; }
                else             { if (n >= 11 && n < 14) v = pd2_w[k*3 + (n-11)]; }
            }
            d2[i] = f2bf(v);
        }
    }
}

// ---------------------------------------------------------------------------
// k_mfma: fully wave-independent (no __syncthreads, no atomics). Each wave:
// 2 chunks x 16 graphs, private LDS slices, weight fragments in VGPRs.
// Boundary-flag written to a per-graph byte array (contention-free).
// C/D layout (m89): col=lane&15, row=(lane>>4)*4+reg.
// ---------------------------------------------------------------------------
__global__ __launch_bounds__(256)
void k_mfma(const float* __restrict__ z, const float* __restrict__ tpr,
            const float* __restrict__ lin_b,
            const u16* __restrict__ lint, const u16* __restrict__ w1t3,
            const u16* __restrict__ w2t3,
            const float* __restrict__ nn1_b, const float* __restrict__ nd1_b,
            const float* __restrict__ pd1_b,
            const float* __restrict__ nn2_b, const float* __restrict__ nd2_b,
            const float* __restrict__ pd2_b,
            const float* __restrict__ bnc,
            const float* __restrict__ nsc, const float* __restrict__ nsh,
            const float* __restrict__ psc, const float* __restrict__ psh,
            float* __restrict__ nf_g, float* __restrict__ pos_g,
            int* __restrict__ nn_int, float* __restrict__ out_nn,
            u8* __restrict__ flag, int B)
{
    __shared__ __align__(16) u16 sX[4][16*RS];
    __shared__ __align__(16) u16 sH[4][16*RS];
    __shared__ __align__(16) u16 sT[4][16*RS];

    const int t    = threadIdx.x;
    const int lane = t & 63;
    const int w    = t >> 6;
    u16* mX = sX[w];
    u16* mH = sH[w];
    u16* mT = sT[w];

    const int W = blockIdx.x * 4 + w;            // global wave id

    if (lane < 16) {
        mX[lane*RS + 33] = 0;
        u32* p = (u32*)(mX + lane*RS + 34);
        #pragma unroll
        for (int q = 0; q < 15; q++) p[q] = 0;
    }

    auto gfrag = [&](const u16* base, int row0, int ks) -> short8v {
        const uint4 v = *(const uint4*)(base + (row0 + (lane & 15))*RS + ks*32 + ((lane >> 4) * 8));
        return __builtin_bit_cast(short8v, v);
    };
    short8v fLin[4][2], fW[3][4][2], fH2[3][2];
    #pragma unroll
    for (int nt = 0; nt < 4; nt++)
        #pragma unroll
        for (int ks = 0; ks < 2; ks++)
            fLin[nt][ks] = gfrag(lint, nt*16, ks);
    #pragma unroll
    for (int b = 0; b < 3; b++)
        #pragma unroll
        for (int nt = 0; nt < 4; nt++)
            #pragma unroll
            for (int ks = 0; ks < 2; ks++)
                fW[b][nt][ks] = gfrag(w1t3 + (size_t)b*64*RS, nt*16, ks);
    #pragma unroll
    for (int b = 0; b < 3; b++)
        #pragma unroll
        for (int ks = 0; ks < 2; ks++)
            fH2[b][ks] = gfrag(w2t3 + (size_t)b*16*RS, 0, ks);

    const int col = lane & 15;
    float bLin[4], bB1[3][4], bSc[2][4], bBi[2][4];
    #pragma unroll
    for (int nt = 0; nt < 4; nt++) {
        const int c = nt*16 + col;
        bLin[nt]    = lin_b[c];
        bB1[0][nt]  = nn1_b[c];
        bB1[1][nt]  = nd1_b[c];
        bB1[2][nt]  = pd1_b[c];
        bSc[0][nt]  = bnc[c];        bBi[0][nt] = bnc[64 + c];
        bSc[1][nt]  = bnc[128 + c];  bBi[1][nt] = bnc[192 + c];
    }
    const float epb = (col < 11) ? nd2_b[col] : (col < 14) ? pd2_b[col - 11] : 0.f;
    const float nn2b = nn2_b[0];
    const float a_ns = nsc[0], a_nh = nsh[0], a_ps = psc[0], a_ph = psh[0];

    auto ldfrag = [&](const u16* base, int ks) -> short8v {
        const uint4 v = *(const uint4*)(base + (lane & 15)*RS + ks*32 + ((lane >> 4) * 8));
        return __builtin_bit_cast(short8v, v);
    };

    #pragma unroll 1
    for (int c = 0; c < 2; c++) {
        const int gb = (W*2 + c) * 16;
        if (gb >= B) break;

        // stage X
        {
            const float4* zb = (const float4*)(z + (size_t)gb * 32);
            const float4 v0 = zb[(lane >> 2)*8 + (lane & 3)*2];
            const float4 v1 = zb[(lane >> 2)*8 + (lane & 3)*2 + 1];
            const float xv[8] = {v0.x, v0.y, v0.z, v0.w, v1.x, v1.y, v1.z, v1.w};
            u32 pk[4];
            #pragma unroll
            for (int q = 0; q < 4; q++)
                pk[q] = (u32)f2bf(xv[2*q]) | ((u32)f2bf(xv[2*q+1]) << 16);
            *(uint4*)(mX + (lane >> 2)*RS + (lane & 3)*8) = *(uint4*)pk;
            if (lane < 16) mX[lane*RS + 32] = f2bf(tpr[gb + lane]);
        }

        // phase A
        const short8v a0 = ldfrag(mX, 0);
        const short8v a1 = ldfrag(mX, 1);
        #pragma unroll
        for (int nt = 0; nt < 4; nt++) {
            f32x4 acc = {0.f, 0.f, 0.f, 0.f};
            acc = __builtin_amdgcn_mfma_f32_16x16x32_bf16(a0, fLin[nt][0], acc, 0, 0, 0);
            acc = __builtin_amdgcn_mfma_f32_16x16x32_bf16(a1, fLin[nt][1], acc, 0, 0, 0);
            const float bias = bLin[nt];
            #pragma unroll
            for (int r = 0; r < 4; r++)
                mH[((lane >> 4)*4 + r)*RS + nt*16 + col] = f2bf(acc[r] + bias);
        }

        // branches
        const short8v h0 = ldfrag(mH, 0);
        const short8v h1 = ldfrag(mH, 1);
        f32x4 acc2 = {0.f, 0.f, 0.f, 0.f};
        #pragma unroll
        for (int b = 0; b < 3; b++) {
            #pragma unroll
            for (int nt = 0; nt < 4; nt++) {
                f32x4 acc = {0.f, 0.f, 0.f, 0.f};
                acc = __builtin_amdgcn_mfma_f32_16x16x32_bf16(h0, fW[b][nt][0], acc, 0, 0, 0);
                acc = __builtin_amdgcn_mfma_f32_16x16x32_bf16(h1, fW[b][nt][1], acc, 0, 0, 0);
                const float bb = bB1[b][nt];
                const float sc = (b > 0) ? bSc[b-1][nt] : 0.f;
                const float bi = (b > 0) ? bBi[b-1][nt] : 0.f;
                #pragma unroll
                for (int r = 0; r < 4; r++) {
                    float rv = acc[r] + bb;
                    rv = rv > 0.f ? rv : 0.f;
                    const float tv = (b == 0) ? rv : fmaf(rv, sc, bi);
                    mT[((lane >> 4)*4 + r)*RS + nt*16 + col] = f2bf(tv);
                }
            }
            const short8v t0 = ldfrag(mT, 0);
            const short8v t1 = ldfrag(mT, 1);
            acc2 = __builtin_amdgcn_mfma_f32_16x16x32_bf16(t0, fH2[b][0], acc2, 0, 0, 0);
            acc2 = __builtin_amdgcn_mfma_f32_16x16x32_bf16(t1, fH2[b][1], acc2, 0, 0, 0);
        }

        // epilogue
        #pragma unroll
        for (int r = 0; r < 4; r++) {
            const int g = gb + (lane >> 4)*4 + r;
            const float v = acc2[r];
            if (col < 11) {
                nf_g[(size_t)g*NDF + col] = fmaf(v + epb, a_ns, a_nh);
            } else if (col < 14) {
                pos_g[(size_t)g*3 + (col - 11)] = fmaf(v + epb, a_ps, a_ph);
            } else if (col == 14) {
                const float logit = v + nn2b;
                const float arg = fmaf(1.f / (1.f + expf(-logit)), 30.f, 5.f);
                const int n = (int)arg;
                nn_int[g] = n;
                out_nn[g] = (float)n;
                flag[g] = (fabsf(arg - rintf(arg)) < 0.30f) ? 1 : 0;   // no atomics
            }
        }
    }
    (void)B;
}

// ---------------------------------------------------------------------------
// k_fix: exact f64 re-derivation for flagged graphs. Grid-stride over all B;
// wave-uniform flag check skips unflagged. h staged in per-wave LDS (f64),
// consumed via double2 broadcast reads (fewer ds ops than shfl chains).
// ---------------------------------------------------------------------------
__global__ __launch_bounds__(256)
void k_fix(const float* __restrict__ z, const float* __restrict__ tpr,
           const float* __restrict__ lin_w, const float* __restrict__ lin_b,
           const float* __restrict__ nn1_w, const float* __restrict__ nn1_b,
           const float* __restrict__ nn2_w, const float* __restrict__ nn2_b,
           const u8* __restrict__ flag, int* __restrict__ nn_int,
           float* __restrict__ out_nn, int B)
{
    __shared__ __align__(16) double hb[4][64];
    const int lane = threadIdx.x & 63;
    const int w = threadIdx.x >> 6;
    const int W = (blockIdx.x * 256 + threadIdx.x) >> 6;   // 4096 waves
    const int gpw = B / 4096;                              // 32 graphs/wave
    const int g0 = W * gpw;
    const double b2 = (double)nn2_b[0];

    for (int i = 0; i < gpw; i++) {
        const int g = g0 + i;
        if (!flag[g]) continue;                            // wave-uniform skip

        // lane k computes h_k in f64 (4 chains)
        double h0 = (double)lin_b[lane], h1 = 0.0, h2 = 0.0, h3 = 0.0;
        for (int j = 0; j < 32; j += 4) {
            h0 = fma((double)z[(size_t)g*32 + j],     (double)lin_w[j*64 + lane],     h0);
            h1 = fma((double)z[(size_t)g*32 + j + 1], (double)lin_w[(j+1)*64 + lane], h1);
            h2 = fma((double)z[(size_t)g*32 + j + 2], (double)lin_w[(j+2)*64 + lane], h2);
            h3 = fma((double)z[(size_t)g*32 + j + 3], (double)lin_w[(j+3)*64 + lane], h3);
        }
        h0 = fma((double)tpr[g], (double)lin_w[32*64 + lane], h0);
        hb[w][lane] = (h0 + h1) + (h2 + h3);

        // lane o: a_o via double2 broadcast reads of h
        const double2* hp = (const double2*)hb[w];
        double a0 = (double)nn1_b[lane], a1 = 0.0, a2 = 0.0, a3 = 0.0;
        for (int m = 0; m < 16; m++) {
            const double2 p = hp[2*m];
            const double2 q = hp[2*m + 1];
            a0 = fma(p.x, (double)nn1_w[(4*m+0)*64 + lane], a0);
            a1 = fma(p.y, (double)nn1_w[(4*m+1)*64 + lane], a1);
            a2 = fma(q.x, (double)nn1_w[(4*m+2)*64 + lane], a2);
            a3 = fma(q.y, (double)nn1_w[(4*m+3)*64 + lane], a3);
        }
        const double a = (a0 + a1) + (a2 + a3);
        double v = (a > 0.0) ? a * (double)nn2_w[lane] : 0.0;
        for (int d = 32; d > 0; d >>= 1) v += __shfl_xor(v, d);
        const double logit = v + b2;

        if (lane == 0) {
            const double sg = 1.0 / (1.0 + exp(-logit));
            const int n = (int)(sg * 30.0 + 5.0);
            nn_int[g] = n;
            out_nn[g] = (float)n;
        }
    }
}

// ---------------------------------------------------------------------------
// 2-kernel prefix sum: per-block inclusive (part) + block-sum scan (boff).
// ---------------------------------------------------------------------------
__global__ __launch_bounds__(256)
void k_scan1(const int* __restrict__ a, int* __restrict__ part, int* __restrict__ bsum)
{
    __shared__ int s[256];
    const int t = threadIdx.x;
    const int g = blockIdx.x * 256 + t;
    const int v = a[g];
    s[t] = v;
    __syncthreads();
    for (int d = 1; d < 256; d <<= 1) {
        const int x = s[t];
        const int add = (t >= d) ? s[t - d] : 0;
        __syncthreads();
        s[t] = x + add;
        __syncthreads();
    }
    part[g] = s[t];
    if (t == 255) bsum[blockIdx.x] = s[255];
}

__global__ void k_scan2(const int* __restrict__ bsum, int* __restrict__ boff, int nb)
{
    __shared__ int s[1024];
    const int t = threadIdx.x;     // nb threads (512)
    const int v = bsum[t];
    s[t] = v;
    __syncthreads();
    for (int d = 1; d < nb; d <<= 1) {
        const int x = s[t];
        const int add = (t >= d) ? s[t - d] : 0;
        __syncthreads();
        s[t] = x + add;
        __syncthreads();
    }
    boff[t] = s[t] - v;            // exclusive
    if (t == nb - 1) boff[nb] = s[t];
}

// ---------------------------------------------------------------------------
// k_expand: 2 rows/thread, two-level binary search, LDS repack, float4 stores.
// Rows >= total repeat graph B-1 (JAX total_repeat_length padding).
// ---------------------------------------------------------------------------
__global__ __launch_bounds__(256)
void k_expand(const int* __restrict__ part, const int* __restrict__ boff,
              const float* __restrict__ nf_g, const float* __restrict__ pos_g,
              float* __restrict__ out, int B, int T, int nb)
{
    __shared__ __align__(16) float s_nf[512*NDF];
    __shared__ __align__(16) float s_ps[512*3];
    const int t = threadIdx.x;
    const int r0 = blockIdx.x * 512 + 2*t;

    int blo = 0, bhi = nb - 1;
    while (blo < bhi) {
        const int m = (blo + bhi + 1) >> 1;
        if (boff[m] <= r0) blo = m; else bhi = m - 1;
    }
    const int bi = blo;
    const int lr = r0 - boff[bi];
    int lo = 0, hi2 = 256;
    while (lo < hi2) {
        const int m = (lo + hi2) >> 1;
        if (part[bi*256 + m] <= lr) lo = m + 1; else hi2 = m;
    }
    int i0 = bi*256 + lo;
    i0 = (i0 < B) ? i0 : B - 1;
    const int Ci0 = boff[i0 >> 8] + part[i0];
    const int i1 = ((r0 + 1) >= Ci0 && i0 < B - 1) ? i0 + 1 : i0;

    #pragma unroll
    for (int j = 0; j < NDF; j++) {
        s_nf[(2*t)*NDF + j]     = nf_g[(size_t)i0*NDF + j];
        s_nf[(2*t + 1)*NDF + j] = nf_g[(size_t)i1*NDF + j];
    }
    #pragma unroll
    for (int j = 0; j < 3; j++) {
        s_ps[(2*t)*3 + j]     = pos_g[(size_t)i0*3 + j];
        s_ps[(2*t + 1)*3 + j] = pos_g[(size_t)i1*3 + j];
    }
    __syncthreads();

    float4* onf = (float4*)(out + (size_t)blockIdx.x * 512 * NDF);
    const float4* snf = (const float4*)s_nf;
    #pragma unroll
    for (int q = 0; q < 6; q++) {
        const int idx = q*256 + t;
        if (idx < 512*NDF/4) onf[idx] = snf[idx];
    }
    float4* ops = (float4*)(out + (size_t)T*NDF + (size_t)blockIdx.x * 512 * 3);
    const float4* sps = (const float4*)s_ps;
    #pragma unroll
    for (int q = 0; q < 2; q++) {
        const int idx = q*256 + t;
        if (idx < 384) ops[idx] = sps[idx];
    }
}

// ---------------------------------------------------------------------------
extern "C" void kernel_launch(void* const* d_in, const int* in_sizes, int n_in,
                              void* d_out, int out_size, void* d_ws, size_t ws_size,
                              hipStream_t stream)
{
    const float* z     = (const float*)d_in[0];
    const float* tpr   = (const float*)d_in[1];
    const int    B     = in_sizes[1];
    const int    T     = B * MAXN;

    const float* lin_w = (const float*)d_in[3];
    const float* lin_b = (const float*)d_in[4];
    const float* nn1_w = (const float*)d_in[5];
    const float* nn1_b = (const float*)d_in[6];
    const float* nn2_w = (const float*)d_in[7];
    const float* nn2_b = (const float*)d_in[8];
    const float* nd1_w = (const float*)d_in[9];
    const float* nd1_b = (const float*)d_in[10];
    const float* nd_g  = (const float*)d_in[11];
    const float* nd_be = (const float*)d_in[12];
    const float* nd_rm = (const float*)d_in[13];
    const float* nd_rv = (const float*)d_in[14];
    const float* nd2_w = (const float*)d_in[15];
    const float* nd2_b = (const float*)d_in[16];
    const float* pd1_w = (const float*)d_in[17];
    const float* pd1_b = (const float*)d_in[18];
    const float* pd_g  = (const float*)d_in[19];
    const float* pd_be = (const float*)d_in[20];
    const float* pd_rm = (const float*)d_in[21];
    const float* pd_rv = (const float*)d_in[22];
    const float* pd2_w = (const float*)d_in[23];
    const float* pd2_b = (const float*)d_in[24];
    const float* nsc   = (const float*)d_in[25];
    const float* nsh   = (const float*)d_in[26];
    const float* psc   = (const float*)d_in[27];
    const float* psh   = (const float*)d_in[28];

    float* out = (float*)d_out;

    char* wsp = (char*)d_ws;
    size_t off = 0;
    auto take = [&](size_t bytes) { void* p = wsp + off; off = (off + bytes + 255) & ~(size_t)255; return p; };

    u16*   lint  = (u16*)take(64*RS*sizeof(u16));
    u16*   w1t3  = (u16*)take(3*64*RS*sizeof(u16));
    u16*   w2t3  = (u16*)take(3*16*RS*sizeof(u16));
    float* bnc   = (float*)take(256*sizeof(float));
    u8*    flag  = (u8*)take((size_t)B);
    float* nf_g  = (float*)take((size_t)B*NDF*sizeof(float));
    float* pos_g = (float*)take((size_t)B*3*sizeof(float));
    int*   nn_i  = (int*)take((size_t)B*sizeof(int));
    int*   part  = (int*)take((size_t)B*sizeof(int));
    int*   bsum  = (int*)take(4096*sizeof(int));
    int*   boff  = (int*)take(4096*sizeof(int));

    const int nb = B / 256;   // 512

    k_prep<<<16, 256, 0, stream>>>(lin_w, nn1_w, nn2_w, nd1_w, nd2_w, pd1_w, pd2_w,
                                   nd_g, nd_be, nd_rm, nd_rv,
                                   pd_g, pd_be, pd_rm, pd_rv,
                                   lint, w1t3, w2t3, bnc);

    k_mfma<<<B/128, 256, 0, stream>>>(z, tpr, lin_b, lint, w1t3, w2t3,
                                      nn1_b, nd1_b, pd1_b, nn2_b, nd2_b, pd2_b,
                                      bnc, nsc, nsh, psc, psh,
                                      nf_g, pos_g, nn_i, out + (size_t)T*14,
                                      flag, B);

    k_fix<<<1024, 256, 0, stream>>>(z, tpr, lin_w, lin_b, nn1_w, nn1_b, nn2_w, nn2_b,
                                    flag, nn_i, out + (size_t)T*14, B);

    k_scan1<<<nb, 256, 0, stream>>>(nn_i, part, bsum);
    k_scan2<<<1, nb, 0, stream>>>(bsum, boff, nb);

    k_expand<<<T/512, 256, 0, stream>>>(part, boff, nf_g, pos_g, out, B, T, nb);

    (void)n_in; (void)out_size; (void)ws_size;
}

// Round 12
// 141.246 us; speedup vs baseline: 4.6174x; 1.4687x over previous
//
#include <hip/hip_runtime.h>
#include <math.h>

typedef unsigned int u32;
typedef unsigned short u16;
typedef unsigned char u8;
typedef __attribute__((ext_vector_type(8))) short short8v;   // 8 bf16 = 4 VGPR
typedef __attribute__((ext_vector_type(4))) float f32x4;

#define NDF 11
#define MAXN 35
#define RS 72          // padded row stride in bf16 elems (144 B; 16B-aligned rows)

__device__ __forceinline__ u16 f2bf(float x) {
    u32 b = __float_as_uint(x);
    u32 r = (b + 0x7fffu + ((b >> 16) & 1u)) >> 16;
    return (u16)r;
}
__device__ __forceinline__ float bf2f(u16 h) {
    return __uint_as_float(((u32)h) << 16);
}
__device__ __forceinline__ void splitbf(float x, u16& hi, u16& lo) {
    hi = f2bf(x);
    lo = f2bf(x - bf2f(hi));
}

// ---------------------------------------------------------------------------
// k_prep: split-bf16 (hi|lo planes) transposed weight images + BN constants.
//   lint  [2][64][RS]   : lin^T
//   w1t3  [3][2][64][RS]: {nn1,nd1,pd1}^T
//   w2t3  [3][2][16][RS]: head^T slices (b0: col14=nn2; b1: cols0-10=nd2;
//                         b2: cols11-13=pd2; rest 0)
// ---------------------------------------------------------------------------
__global__ void k_prep(const float* __restrict__ lin_w,
                       const float* __restrict__ nn1_w, const float* __restrict__ nn2_w,
                       const float* __restrict__ nd1_w, const float* __restrict__ nd2_w,
                       const float* __restrict__ pd1_w, const float* __restrict__ pd2_w,
                       const float* __restrict__ nd_g, const float* __restrict__ nd_be,
                       const float* __restrict__ nd_rm, const float* __restrict__ nd_rv,
                       const float* __restrict__ pd_g, const float* __restrict__ pd_be,
                       const float* __restrict__ pd_rm, const float* __restrict__ pd_rv,
                       u16* __restrict__ lint, u16* __restrict__ w1t3,
                       u16* __restrict__ w2t3, float* __restrict__ bnc)
{
    const int t0 = blockIdx.x * 256 + threadIdx.x;     // 16 blocks -> 4096
    if (t0 < 64) {
        const float sc = nd_g[t0] / sqrtf(nd_rv[t0] + 1e-5f);
        bnc[t0]       = sc;
        bnc[64 + t0]  = nd_be[t0] - nd_rm[t0] * sc;
        const float sp = pd_g[t0] / sqrtf(pd_rv[t0] + 1e-5f);
        bnc[128 + t0] = sp;
        bnc[192 + t0] = pd_be[t0] - pd_rm[t0] * sp;
    }
    for (int i = t0; i < 64*RS; i += 4096) {
        const int n = i / RS, k = i % RS;
        const float v = (k < 33) ? lin_w[k*64 + n] : 0.f;
        u16 h, l; splitbf(v, h, l);
        lint[i] = h; lint[64*RS + i] = l;
    }
    for (int b = 0; b < 3; b++) {
        const float* M = (b == 0) ? nn1_w : (b == 1) ? nd1_w : pd1_w;
        u16* dst = w1t3 + (size_t)b * 2 * 64 * RS;
        for (int i = t0; i < 64*RS; i += 4096) {
            const int o = i / RS, k = i % RS;
            const float v = (k < 64) ? M[k*64 + o] : 0.f;
            u16 h, l; splitbf(v, h, l);
            dst[i] = h; dst[64*RS + i] = l;
        }
        u16* d2 = w2t3 + (size_t)b * 2 * 16 * RS;
        for (int i = t0; i < 16*RS; i += 4096) {
            const int n = i / RS, k = i % RS;
            float v = 0.f;
            if (k < 64) {
                if (b == 0)      { if (n == 14)           v = nn2_w[k]; }
                else if (b == 1) { if (n < 11)            v = nd2_w[k*11 + n]; }
                else             { if (n >= 11 && n < 14) v = pd2_w[k*3 + (n-11)]; }
            }
            u16 h, l; splitbf(v, h, l);
            d2[i] = h; d2[16*RS + i] = l;
        }
    }
}

// ---------------------------------------------------------------------------
// k_mfma: fully wave-independent (no barriers, no atomics). Each wave:
// 2 chunks x 16 graphs, private LDS slices (hi|lo planes), hi weight frags
// in VGPRs, lo frags loaded from L2 at use. Split-bf16 precision (3-term
// MFMA) for phase A and the nn branch only; decode branches single-bf16.
// C/D layout (m89): col=lane&15, row=(lane>>4)*4+reg.
// ---------------------------------------------------------------------------
__global__ __launch_bounds__(256)
void k_mfma(const float* __restrict__ z, const float* __restrict__ tpr,
            const float* __restrict__ lin_b,
            const u16* __restrict__ lint, const u16* __restrict__ w1t3,
            const u16* __restrict__ w2t3,
            const float* __restrict__ nn1_b, const float* __restrict__ nd1_b,
            const float* __restrict__ pd1_b,
            const float* __restrict__ nn2_b, const float* __restrict__ nd2_b,
            const float* __restrict__ pd2_b,
            const float* __restrict__ bnc,
            const float* __restrict__ nsc, const float* __restrict__ nsh,
            const float* __restrict__ psc, const float* __restrict__ psh,
            float* __restrict__ nf_g, float* __restrict__ pos_g,
            int* __restrict__ nn_int, float* __restrict__ out_nn,
            u8* __restrict__ flag, int B)
{
    __shared__ __align__(16) u16 sX[4][2*16*RS];   // hi | lo planes
    __shared__ __align__(16) u16 sH[4][2*16*RS];
    __shared__ __align__(16) u16 sT[4][2*16*RS];

    const int t    = threadIdx.x;
    const int lane = t & 63;
    const int w    = t >> 6;
    u16* mX = sX[w];
    u16* mH = sH[w];
    u16* mT = sT[w];

    const int W = blockIdx.x * 4 + w;            // global wave id

    // zero X pad cols 33..63 on both planes (chunks rewrite only cols 0..32)
    if (lane < 16) {
        #pragma unroll
        for (int pl = 0; pl < 2; pl++) {
            u16* base = mX + pl*16*RS;
            base[lane*RS + 33] = 0;
            u32* p = (u32*)(base + lane*RS + 34);
            #pragma unroll
            for (int q = 0; q < 15; q++) p[q] = 0;
        }
    }

    auto gfrag = [&](const u16* base, int row0, int ks) -> short8v {
        const uint4 v = *(const uint4*)(base + (row0 + (lane & 15))*RS + ks*32 + ((lane >> 4) * 8));
        return __builtin_bit_cast(short8v, v);
    };
    // hi fragments preloaded (L2-hot); lo fragments loaded at use
    short8v fLin[4][2], fW[3][4][2], fH2[3][2];
    #pragma unroll
    for (int nt = 0; nt < 4; nt++)
        #pragma unroll
        for (int ks = 0; ks < 2; ks++)
            fLin[nt][ks] = gfrag(lint, nt*16, ks);
    #pragma unroll
    for (int b = 0; b < 3; b++)
        #pragma unroll
        for (int nt = 0; nt < 4; nt++)
            #pragma unroll
            for (int ks = 0; ks < 2; ks++)
                fW[b][nt][ks] = gfrag(w1t3 + (size_t)b*2*64*RS, nt*16, ks);
    #pragma unroll
    for (int b = 0; b < 3; b++)
        #pragma unroll
        for (int ks = 0; ks < 2; ks++)
            fH2[b][ks] = gfrag(w2t3 + (size_t)b*2*16*RS, 0, ks);

    const int col = lane & 15;
    float bLin[4], bB1[3][4], bSc[2][4], bBi[2][4];
    #pragma unroll
    for (int nt = 0; nt < 4; nt++) {
        const int c = nt*16 + col;
        bLin[nt]    = lin_b[c];
        bB1[0][nt]  = nn1_b[c];
        bB1[1][nt]  = nd1_b[c];
        bB1[2][nt]  = pd1_b[c];
        bSc[0][nt]  = bnc[c];        bBi[0][nt] = bnc[64 + c];
        bSc[1][nt]  = bnc[128 + c];  bBi[1][nt] = bnc[192 + c];
    }
    const float epb = (col < 11) ? nd2_b[col] : (col < 14) ? pd2_b[col - 11] : 0.f;
    const float nn2b = nn2_b[0];
    const float a_ns = nsc[0], a_nh = nsh[0], a_ps = psc[0], a_ph = psh[0];

    auto ldfrag = [&](const u16* base, int ks) -> short8v {
        const uint4 v = *(const uint4*)(base + (lane & 15)*RS + ks*32 + ((lane >> 4) * 8));
        return __builtin_bit_cast(short8v, v);
    };

    #pragma unroll 1
    for (int c = 0; c < 2; c++) {
        const int gb = (W*2 + c) * 16;
        if (gb >= B) break;

        // ---- stage X (hi|lo planes) ----
        {
            const float4* zb = (const float4*)(z + (size_t)gb * 32);
            const float4 v0 = zb[(lane >> 2)*8 + (lane & 3)*2];
            const float4 v1 = zb[(lane >> 2)*8 + (lane & 3)*2 + 1];
            const float xv[8] = {v0.x, v0.y, v0.z, v0.w, v1.x, v1.y, v1.z, v1.w};
            u32 pkh[4], pkl[4];
            #pragma unroll
            for (int q = 0; q < 4; q++) {
                u16 h0, l0, h1, l1;
                splitbf(xv[2*q], h0, l0);
                splitbf(xv[2*q+1], h1, l1);
                pkh[q] = (u32)h0 | ((u32)h1 << 16);
                pkl[q] = (u32)l0 | ((u32)l1 << 16);
            }
            *(uint4*)(mX + (lane >> 2)*RS + (lane & 3)*8) = *(uint4*)pkh;
            *(uint4*)(mX + 16*RS + (lane >> 2)*RS + (lane & 3)*8) = *(uint4*)pkl;
            if (lane < 16) {
                u16 h, l; splitbf(tpr[gb + lane], h, l);
                mX[lane*RS + 32] = h;
                mX[16*RS + lane*RS + 32] = l;
            }
        }

        // ---- phase A (split, 6 MFMA/nt): H = X @ lin + lin_b ----
        const short8v a0h = ldfrag(mX, 0);
        const short8v a1h = ldfrag(mX, 1);
        const short8v a0l = ldfrag(mX + 16*RS, 0);
        const short8v a1l = ldfrag(mX + 16*RS, 1);
        #pragma unroll
        for (int nt = 0; nt < 4; nt++) {
            const short8v bl0 = gfrag(lint + 64*RS, nt*16, 0);
            const short8v bl1 = gfrag(lint + 64*RS, nt*16, 1);
            f32x4 acc = {0.f, 0.f, 0.f, 0.f};
            acc = __builtin_amdgcn_mfma_f32_16x16x32_bf16(a0h, fLin[nt][0], acc, 0, 0, 0);
            acc = __builtin_amdgcn_mfma_f32_16x16x32_bf16(a1h, fLin[nt][1], acc, 0, 0, 0);
            acc = __builtin_amdgcn_mfma_f32_16x16x32_bf16(a0h, bl0, acc, 0, 0, 0);
            acc = __builtin_amdgcn_mfma_f32_16x16x32_bf16(a1h, bl1, acc, 0, 0, 0);
            acc = __builtin_amdgcn_mfma_f32_16x16x32_bf16(a0l, fLin[nt][0], acc, 0, 0, 0);
            acc = __builtin_amdgcn_mfma_f32_16x16x32_bf16(a1l, fLin[nt][1], acc, 0, 0, 0);
            const float bias = bLin[nt];
            #pragma unroll
            for (int r = 0; r < 4; r++) {
                const int row = (lane >> 4)*4 + r;
                u16 hh, hl; splitbf(acc[r] + bias, hh, hl);
                mH[row*RS + nt*16 + col] = hh;
                mH[16*RS + row*RS + nt*16 + col] = hl;
            }
        }

        const short8v h0h = ldfrag(mH, 0);
        const short8v h1h = ldfrag(mH, 1);
        f32x4 acc2 = {0.f, 0.f, 0.f, 0.f};

        // ---- nn branch (b=0, split): hidden + relu -> T(hi|lo), head ----
        {
            const short8v h0l = ldfrag(mH + 16*RS, 0);
            const short8v h1l = ldfrag(mH + 16*RS, 1);
            const u16* wlo = w1t3 + 64*RS;   // b=0 lo plane
            #pragma unroll
            for (int nt = 0; nt < 4; nt++) {
                const short8v wl0 = gfrag(wlo, nt*16, 0);
                const short8v wl1 = gfrag(wlo, nt*16, 1);
                f32x4 acc = {0.f, 0.f, 0.f, 0.f};
                acc = __builtin_amdgcn_mfma_f32_16x16x32_bf16(h0h, fW[0][nt][0], acc, 0, 0, 0);
                acc = __builtin_amdgcn_mfma_f32_16x16x32_bf16(h1h, fW[0][nt][1], acc, 0, 0, 0);
                acc = __builtin_amdgcn_mfma_f32_16x16x32_bf16(h0h, wl0, acc, 0, 0, 0);
                acc = __builtin_amdgcn_mfma_f32_16x16x32_bf16(h1h, wl1, acc, 0, 0, 0);
                acc = __builtin_amdgcn_mfma_f32_16x16x32_bf16(h0l, fW[0][nt][0], acc, 0, 0, 0);
                acc = __builtin_amdgcn_mfma_f32_16x16x32_bf16(h1l, fW[0][nt][1], acc, 0, 0, 0);
                const float bb = bB1[0][nt];
                #pragma unroll
                for (int r = 0; r < 4; r++) {
                    const int row = (lane >> 4)*4 + r;
                    float rv = acc[r] + bb;
                    rv = rv > 0.f ? rv : 0.f;
                    u16 th, tl; splitbf(rv, th, tl);
                    mT[row*RS + nt*16 + col] = th;
                    mT[16*RS + row*RS + nt*16 + col] = tl;
                }
            }
            const short8v t0h = ldfrag(mT, 0);
            const short8v t1h = ldfrag(mT, 1);
            const short8v t0l = ldfrag(mT + 16*RS, 0);
            const short8v t1l = ldfrag(mT + 16*RS, 1);
            const short8v g2l0 = gfrag(w2t3 + 16*RS, 0, 0);
            const short8v g2l1 = gfrag(w2t3 + 16*RS, 0, 1);
            acc2 = __builtin_amdgcn_mfma_f32_16x16x32_bf16(t0h, fH2[0][0], acc2, 0, 0, 0);
            acc2 = __builtin_amdgcn_mfma_f32_16x16x32_bf16(t1h, fH2[0][1], acc2, 0, 0, 0);
            acc2 = __builtin_amdgcn_mfma_f32_16x16x32_bf16(t0h, g2l0, acc2, 0, 0, 0);
            acc2 = __builtin_amdgcn_mfma_f32_16x16x32_bf16(t1h, g2l1, acc2, 0, 0, 0);
            acc2 = __builtin_amdgcn_mfma_f32_16x16x32_bf16(t0l, fH2[0][0], acc2, 0, 0, 0);
            acc2 = __builtin_amdgcn_mfma_f32_16x16x32_bf16(t1l, fH2[0][1], acc2, 0, 0, 0);
        }

        // ---- decode branches (b=1,2, single-bf16) ----
        #pragma unroll
        for (int b = 1; b < 3; b++) {
            #pragma unroll
            for (int nt = 0; nt < 4; nt++) {
                f32x4 acc = {0.f, 0.f, 0.f, 0.f};
                acc = __builtin_amdgcn_mfma_f32_16x16x32_bf16(h0h, fW[b][nt][0], acc, 0, 0, 0);
                acc = __builtin_amdgcn_mfma_f32_16x16x32_bf16(h1h, fW[b][nt][1], acc, 0, 0, 0);
                const float bb = bB1[b][nt];
                const float sc = bSc[b-1][nt];
                const float bi = bBi[b-1][nt];
                #pragma unroll
                for (int r = 0; r < 4; r++) {
                    const int row = (lane >> 4)*4 + r;
                    float rv = acc[r] + bb;
                    rv = rv > 0.f ? rv : 0.f;
                    mT[row*RS + nt*16 + col] = f2bf(fmaf(rv, sc, bi));
                }
            }
            const short8v t0 = ldfrag(mT, 0);
            const short8v t1 = ldfrag(mT, 1);
            acc2 = __builtin_amdgcn_mfma_f32_16x16x32_bf16(t0, fH2[b][0], acc2, 0, 0, 0);
            acc2 = __builtin_amdgcn_mfma_f32_16x16x32_bf16(t1, fH2[b][1], acc2, 0, 0, 0);
        }

        // ---- epilogue: cols 0-10 nf, 11-13 pos, 14 logit ----
        #pragma unroll
        for (int r = 0; r < 4; r++) {
            const int g = gb + (lane >> 4)*4 + r;
            const float v = acc2[r];
            if (col < 11) {
                nf_g[(size_t)g*NDF + col] = fmaf(v + epb, a_ns, a_nh);
            } else if (col < 14) {
                pos_g[(size_t)g*3 + (col - 11)] = fmaf(v + epb, a_ps, a_ph);
            } else if (col == 14) {
                const float logit = v + nn2b;
                const float arg = fmaf(1.f / (1.f + expf(-logit)), 30.f, 5.f);
                const int n = (int)arg;
                nn_int[g] = n;
                out_nn[g] = (float)n;
                flag[g] = (fabsf(arg - rintf(arg)) < 0.03f) ? 1 : 0;  // split-precision logit
            }
        }
    }
    (void)B;
}

// ---------------------------------------------------------------------------
// k_fix: exact f64 re-derivation for flagged graphs. Grid-stride over all B;
// wave-uniform flag check skips unflagged (~6% flagged at 0.03 margin).
// ---------------------------------------------------------------------------
__global__ __launch_bounds__(256)
void k_fix(const float* __restrict__ z, const float* __restrict__ tpr,
           const float* __restrict__ lin_w, const float* __restrict__ lin_b,
           const float* __restrict__ nn1_w, const float* __restrict__ nn1_b,
           const float* __restrict__ nn2_w, const float* __restrict__ nn2_b,
           const u8* __restrict__ flag, int* __restrict__ nn_int,
           float* __restrict__ out_nn, int B)
{
    __shared__ __align__(16) double hb[4][64];
    const int lane = threadIdx.x & 63;
    const int w = threadIdx.x >> 6;
    const int W = (blockIdx.x * 256 + threadIdx.x) >> 6;   // 4096 waves
    const int gpw = B / 4096;                              // 32 graphs/wave
    const int g0 = W * gpw;
    const double b2 = (double)nn2_b[0];

    for (int i = 0; i < gpw; i++) {
        const int g = g0 + i;
        if (!flag[g]) continue;                            // wave-uniform skip

        double h0 = (double)lin_b[lane], h1 = 0.0, h2 = 0.0, h3 = 0.0;
        for (int j = 0; j < 32; j += 4) {
            h0 = fma((double)z[(size_t)g*32 + j],     (double)lin_w[j*64 + lane],     h0);
            h1 = fma((double)z[(size_t)g*32 + j + 1], (double)lin_w[(j+1)*64 + lane], h1);
            h2 = fma((double)z[(size_t)g*32 + j + 2], (double)lin_w[(j+2)*64 + lane], h2);
            h3 = fma((double)z[(size_t)g*32 + j + 3], (double)lin_w[(j+3)*64 + lane], h3);
        }
        h0 = fma((double)tpr[g], (double)lin_w[32*64 + lane], h0);
        hb[w][lane] = (h0 + h1) + (h2 + h3);

        const double2* hp = (const double2*)hb[w];
        double a0 = (double)nn1_b[lane], a1 = 0.0, a2 = 0.0, a3 = 0.0;
        for (int m = 0; m < 16; m++) {
            const double2 p = hp[2*m];
            const double2 q = hp[2*m + 1];
            a0 = fma(p.x, (double)nn1_w[(4*m+0)*64 + lane], a0);
            a1 = fma(p.y, (double)nn1_w[(4*m+1)*64 + lane], a1);
            a2 = fma(q.x, (double)nn1_w[(4*m+2)*64 + lane], a2);
            a3 = fma(q.y, (double)nn1_w[(4*m+3)*64 + lane], a3);
        }
        const double a = (a0 + a1) + (a2 + a3);
        double v = (a > 0.0) ? a * (double)nn2_w[lane] : 0.0;
        for (int d = 32; d > 0; d >>= 1) v += __shfl_xor(v, d);
        const double logit = v + b2;

        if (lane == 0) {
            const double sg = 1.0 / (1.0 + exp(-logit));
            const int n = (int)(sg * 30.0 + 5.0);
            nn_int[g] = n;
            out_nn[g] = (float)n;
        }
    }
}

// ---------------------------------------------------------------------------
// 2-kernel prefix sum: per-block inclusive (part) + block-sum scan (boff).
// ---------------------------------------------------------------------------
__global__ __launch_bounds__(256)
void k_scan1(const int* __restrict__ a, int* __restrict__ part, int* __restrict__ bsum)
{
    __shared__ int s[256];
    const int t = threadIdx.x;
    const int g = blockIdx.x * 256 + t;
    const int v = a[g];
    s[t] = v;
    __syncthreads();
    for (int d = 1; d < 256; d <<= 1) {
        const int x = s[t];
        const int add = (t >= d) ? s[t - d] : 0;
        __syncthreads();
        s[t] = x + add;
        __syncthreads();
    }
    part[g] = s[t];
    if (t == 255) bsum[blockIdx.x] = s[255];
}

__global__ void k_scan2(const int* __restrict__ bsum, int* __restrict__ boff, int nb)
{
    __shared__ int s[1024];
    const int t = threadIdx.x;     // nb threads (512)
    const int v = bsum[t];
    s[t] = v;
    __syncthreads();
    for (int d = 1; d < nb; d <<= 1) {
        const int x = s[t];
        const int add = (t >= d) ? s[t - d] : 0;
        __syncthreads();
        s[t] = x + add;
        __syncthreads();
    }
    boff[t] = s[t] - v;            // exclusive
    if (t == nb - 1) boff[nb] = s[t];
}

// ---------------------------------------------------------------------------
// k_expand: 2 rows/thread, two-level binary search, LDS repack, float4 stores.
// Rows >= total repeat graph B-1 (JAX total_repeat_length padding).
// ---------------------------------------------------------------------------
__global__ __launch_bounds__(256)
void k_expand(const int* __restrict__ part, const int* __restrict__ boff,
              const float* __restrict__ nf_g, const float* __restrict__ pos_g,
              float* __restrict__ out, int B, int T, int nb)
{
    __shared__ __align__(16) float s_nf[512*NDF];
    __shared__ __align__(16) float s_ps[512*3];
    const int t = threadIdx.x;
    const int r0 = blockIdx.x * 512 + 2*t;

    int blo = 0, bhi = nb - 1;
    while (blo < bhi) {
        const int m = (blo + bhi + 1) >> 1;
        if (boff[m] <= r0) blo = m; else bhi = m - 1;
    }
    const int bi = blo;
    const int lr = r0 - boff[bi];
    int lo = 0, hi2 = 256;
    while (lo < hi2) {
        const int m = (lo + hi2) >> 1;
        if (part[bi*256 + m] <= lr) lo = m + 1; else hi2 = m;
    }
    int i0 = bi*256 + lo;
    i0 = (i0 < B) ? i0 : B - 1;
    const int Ci0 = boff[i0 >> 8] + part[i0];
    const int i1 = ((r0 + 1) >= Ci0 && i0 < B - 1) ? i0 + 1 : i0;

    #pragma unroll
    for (int j = 0; j < NDF; j++) {
        s_nf[(2*t)*NDF + j]     = nf_g[(size_t)i0*NDF + j];
        s_nf[(2*t + 1)*NDF + j] = nf_g[(size_t)i1*NDF + j];
    }
    #pragma unroll
    for (int j = 0; j < 3; j++) {
        s_ps[(2*t)*3 + j]     = pos_g[(size_t)i0*3 + j];
        s_ps[(2*t + 1)*3 + j] = pos_g[(size_t)i1*3 + j];
    }
    __syncthreads();

    float4* onf = (float4*)(out + (size_t)blockIdx.x * 512 * NDF);
    const float4* snf = (const float4*)s_nf;
    #pragma unroll
    for (int q = 0; q < 6; q++) {
        const int idx = q*256 + t;
        if (idx < 512*NDF/4) onf[idx] = snf[idx];
    }
    float4* ops = (float4*)(out + (size_t)T*NDF + (size_t)blockIdx.x * 512 * 3);
    const float4* sps = (const float4*)s_ps;
    #pragma unroll
    for (int q = 0; q < 2; q++) {
        const int idx = q*256 + t;
        if (idx < 384) ops[idx] = sps[idx];
    }
}

// ---------------------------------------------------------------------------
extern "C" void kernel_launch(void* const* d_in, const int* in_sizes, int n_in,
                              void* d_out, int out_size, void* d_ws, size_t ws_size,
                              hipStream_t stream)
{
    const float* z     = (const float*)d_in[0];
    const float* tpr   = (const float*)d_in[1];
    const int    B     = in_sizes[1];
    const int    T     = B * MAXN;

    const float* lin_w = (const float*)d_in[3];
    const float* lin_b = (const float*)d_in[4];
    const float* nn1_w = (const float*)d_in[5];
    const float* nn1_b = (const float*)d_in[6];
    const float* nn2_w = (const float*)d_in[7];
    const float* nn2_b = (const float*)d_in[8];
    const float* nd1_w = (const float*)d_in[9];
    const float* nd1_b = (const float*)d_in[10];
    const float* nd_g  = (const float*)d_in[11];
    const float* nd_be = (const float*)d_in[12];
    const float* nd_rm = (const float*)d_in[13];
    const float* nd_rv = (const float*)d_in[14];
    const float* nd2_w = (const float*)d_in[15];
    const float* nd2_b = (const float*)d_in[16];
    const float* pd1_w = (const float*)d_in[17];
    const float* pd1_b = (const float*)d_in[18];
    const float* pd_g  = (const float*)d_in[19];
    const float* pd_be = (const float*)d_in[20];
    const float* pd_rm = (const float*)d_in[21];
    const float* pd_rv = (const float*)d_in[22];
    const float* pd2_w = (const float*)d_in[23];
    const float* pd2_b = (const float*)d_in[24];
    const float* nsc   = (const float*)d_in[25];
    const float* nsh   = (const float*)d_in[26];
    const float* psc   = (const float*)d_in[27];
    const float* psh   = (const float*)d_in[28];

    float* out = (float*)d_out;

    char* wsp = (char*)d_ws;
    size_t off = 0;
    auto take = [&](size_t bytes) { void* p = wsp + off; off = (off + bytes + 255) & ~(size_t)255; return p; };

    u16*   lint  = (u16*)take(2*64*RS*sizeof(u16));
    u16*   w1t3  = (u16*)take(3*2*64*RS*sizeof(u16));
    u16*   w2t3  = (u16*)take(3*2*16*RS*sizeof(u16));
    float* bnc   = (float*)take(256*sizeof(float));
    u8*    flag  = (u8*)take((size_t)B);
    float* nf_g  = (float*)take((size_t)B*NDF*sizeof(float));
    float* pos_g = (float*)take((size_t)B*3*sizeof(float));
    int*   nn_i  = (int*)take((size_t)B*sizeof(int));
    int*   part  = (int*)take((size_t)B*sizeof(int));
    int*   bsum  = (int*)take(4096*sizeof(int));
    int*   boff  = (int*)take(4096*sizeof(int));

    const int nb = B / 256;   // 512

    k_prep<<<16, 256, 0, stream>>>(lin_w, nn1_w, nn2_w, nd1_w, nd2_w, pd1_w, pd2_w,
                                   nd_g, nd_be, nd_rm, nd_rv,
                                   pd_g, pd_be, pd_rm, pd_rv,
                                   lint, w1t3, w2t3, bnc);

    k_mfma<<<B/128, 256, 0, stream>>>(z, tpr, lin_b, lint, w1t3, w2t3,
                                      nn1_b, nd1_b, pd1_b, nn2_b, nd2_b, pd2_b,
                                      bnc, nsc, nsh, psc, psh,
                                      nf_g, pos_g, nn_i, out + (size_t)T*14,
                                      flag, B);

    k_fix<<<1024, 256, 0, stream>>>(z, tpr, lin_w, lin_b, nn1_w, nn1_b, nn2_w, nn2_b,
                                    flag, nn_i, out + (size_t)T*14, B);

    k_scan1<<<nb, 256, 0, stream>>>(nn_i, part, bsum);
    k_scan2<<<1, nb, 0, stream>>>(bsum, boff, nb);

    k_expand<<<T/512, 256, 0, stream>>>(part, boff, nf_g, pos_g, out, B, T, nb);

    (void)n_in; (void)out_size; (void)ws_size;
}